// Round 4
// baseline (140.007 us; speedup 1.0000x reference)
//
#include <hip/hip_runtime.h>
#include <math.h>

// Problem dims (from reference): B=4, C=64, T=16, H=128, W=128, fp32.
#define BB 4
#define CC 64
#define TT 16
#define HH 128
#define WW 128
#define HALO 16           // max spatial dilation
#define PW (WW + 2*HALO)  // padded LDS row stride = 160 floats

typedef float f32x4 __attribute__((ext_vector_type(4)));

__device__ __forceinline__ float softplus_f(float x) {
    return (x > 20.0f) ? x : log1pf(expf(x));
}

// One block per (b,c), looping t=0..15.
//  - temporal history (t-1, t-2) kept in registers -> temporal taps are free
//  - plane t+1 PREFETCHED into registers before computing plane t, so the
//    HBM read stream overlaps the LDS+VALU compute phase
//  - spatial taps via full-plane LDS buffer with 16-col replicate halo
__global__ __launch_bounds__(1024, 4) void lap_st_kernel(
    const float* __restrict__ u,
    const float* __restrict__ Ds,   // (3, 64)
    const float* __restrict__ Dt,   // (2, 64)
    float* __restrict__ out)
{
    __shared__ __align__(16) float sm[HH * PW];

    const int bc = blockIdx.x;             // b*C + c, 0..255
    const int c  = bc & (CC - 1);
    const int tid = threadIdx.x;

    const float cs0 = softplus_f(Ds[0 * CC + c]);
    const float cs1 = softplus_f(Ds[1 * CC + c]);
    const float cs2 = softplus_f(Ds[2 * CC + c]);
    const float ct0 = softplus_f(Dt[0 * CC + c]);
    const float ct1 = softplus_f(Dt[1 * CC + c]);
    const float cu = -4.0f * (cs0 + cs1 + cs2) - (ct0 + ct1);

    const size_t bc_off = (size_t)bc * TT * (HH * WW);

    float4 nxt[4], cur[4], pm1[4], pm2[4];

    // prologue: load plane 0 into prefetch registers
    {
        const float4* up4 = (const float4*)(u + bc_off);
        #pragma unroll
        for (int i = 0; i < 4; ++i) nxt[i] = up4[tid + (i << 10)];
    }

    for (int t = 0; t < TT; ++t) {
        f32x4* out4 = (f32x4*)(out + bc_off + (size_t)t * (HH * WW));

        #pragma unroll
        for (int i = 0; i < 4; ++i) cur[i] = nxt[i];

        __syncthreads();   // previous iteration's LDS reads done -> safe to overwrite

        // ---- stage plane t into LDS from registers; halos splatted inline ----
        #pragma unroll
        for (int i = 0; i < 4; ++i) {
            const int k = tid + (i << 10);       // chunk index 0..4095
            const float4 v = cur[i];
            const int row  = k >> 5;             // 32 float4-chunks per row
            const int colc = k & 31;
            *(float4*)&sm[row * PW + HALO + (colc << 2)] = v;
            if (colc == 0) {                      // left replicate halo
                float4 s = make_float4(v.x, v.x, v.x, v.x);
                float* hp = &sm[row * PW];
                *(float4*)&hp[0] = s; *(float4*)&hp[4] = s;
                *(float4*)&hp[8] = s; *(float4*)&hp[12] = s;
            } else if (colc == 31) {              // right replicate halo
                float4 s = make_float4(v.w, v.w, v.w, v.w);
                float* hp = &sm[row * PW + HALO + WW];
                *(float4*)&hp[0] = s; *(float4*)&hp[4] = s;
                *(float4*)&hp[8] = s; *(float4*)&hp[12] = s;
            }
        }

        // ---- prefetch plane t+1 (latency hides under compute below) ----
        if (t < TT - 1) {
            const float4* up4 = (const float4*)(u + bc_off + (size_t)(t + 1) * (HH * WW));
            #pragma unroll
            for (int i = 0; i < 4; ++i) nxt[i] = up4[tid + (i << 10)];
        }

        if (t == 0) {   // causal edge clamp: u[-1] = u[-2] = u[0]
            #pragma unroll
            for (int i = 0; i < 4; ++i) { pm1[i] = cur[i]; pm2[i] = cur[i]; }
        }
        __syncthreads();

        // ---- compute ----
        #pragma unroll
        for (int i = 0; i < 4; ++i) {
            const int k   = tid + (i << 10);
            const int row = k >> 5;
            const int col = (k & 31) << 2;
            const float* rp = &sm[row * PW + HALO];

            const int rU1  = (row >= 1)       ? row - 1  : 0;
            const int rD1  = (row <= HH - 2)  ? row + 1  : HH - 1;
            const int rU4  = (row >= 4)       ? row - 4  : 0;
            const int rD4  = (row <= HH - 5)  ? row + 4  : HH - 1;
            const int rU16 = (row >= 16)      ? row - 16 : 0;
            const int rD16 = (row <= HH - 17) ? row + 16 : HH - 1;

            const float4 c0   = cur[i];   // center from registers
            const float4 vu1  = *(const float4*)&sm[rU1  * PW + HALO + col];
            const float4 vd1  = *(const float4*)&sm[rD1  * PW + HALO + col];
            const float4 vu4  = *(const float4*)&sm[rU4  * PW + HALO + col];
            const float4 vd4  = *(const float4*)&sm[rD4  * PW + HALO + col];
            const float4 vu16 = *(const float4*)&sm[rU16 * PW + HALO + col];
            const float4 vd16 = *(const float4*)&sm[rD16 * PW + HALO + col];
            const float4 l4   = *(const float4*)&rp[col - 4];
            const float4 r4   = *(const float4*)&rp[col + 4];
            const float4 l16  = *(const float4*)&rp[col - 16];
            const float4 r16  = *(const float4*)&rp[col + 16];

            const float4 p1 = pm1[i];
            const float4 p2 = pm2[i];

            f32x4 o;
            o.x = cs0 * (vu1.x + vd1.x + l4.w + c0.y)
                + cs1 * (vu4.x + vd4.x + l4.x + r4.x)
                + cs2 * (vu16.x + vd16.x + l16.x + r16.x)
                + cu * c0.x + ct0 * p1.x + ct1 * p2.x;
            o.y = cs0 * (vu1.y + vd1.y + c0.x + c0.z)
                + cs1 * (vu4.y + vd4.y + l4.y + r4.y)
                + cs2 * (vu16.y + vd16.y + l16.y + r16.y)
                + cu * c0.y + ct0 * p1.y + ct1 * p2.y;
            o.z = cs0 * (vu1.z + vd1.z + c0.y + c0.w)
                + cs1 * (vu4.z + vd4.z + l4.z + r4.z)
                + cs2 * (vu16.z + vd16.z + l16.z + r16.z)
                + cu * c0.z + ct0 * p1.z + ct1 * p2.z;
            o.w = cs0 * (vu1.w + vd1.w + c0.z + r4.x)
                + cs1 * (vu4.w + vd4.w + l4.w + r4.w)
                + cs2 * (vu16.w + vd16.w + l16.w + r16.w)
                + cu * c0.w + ct0 * p1.w + ct1 * p2.w;

            __builtin_nontemporal_store(o, &out4[k]);   // streaming output, never re-read
        }

        // rotate temporal history: t -> t+1
        #pragma unroll
        for (int i = 0; i < 4; ++i) { pm2[i] = pm1[i]; pm1[i] = cur[i]; }
    }
}

extern "C" void kernel_launch(void* const* d_in, const int* in_sizes, int n_in,
                              void* d_out, int out_size, void* d_ws, size_t ws_size,
                              hipStream_t stream) {
    const float* u  = (const float*)d_in[0];
    const float* Ds = (const float*)d_in[1];
    const float* Dt = (const float*)d_in[2];
    float* out = (float*)d_out;

    const int nblocks = BB * CC;   // 256 -> one block per CU
    lap_st_kernel<<<dim3(nblocks), dim3(1024), 0, stream>>>(u, Ds, Dt, out);
}

// Round 5
// 121.081 us; speedup vs baseline: 1.1563x; 1.1563x over previous
//
#include <hip/hip_runtime.h>
#include <math.h>

// Problem dims (from reference): B=4, C=64, T=16, H=128, W=128, fp32.
#define BB 4
#define CC 64
#define TT 16
#define HH 128
#define WW 128
#define HALO 16           // max spatial dilation
#define PW (WW + 2*HALO)  // padded LDS row stride = 160 floats

typedef float f32x4 __attribute__((ext_vector_type(4)));

__device__ __forceinline__ float softplus_f(float x) {
    return (x > 20.0f) ? x : log1pf(expf(x));
}

// Barrier that orders LDS traffic only (s_waitcnt lgkmcnt(0)) and does NOT
// drain vmcnt — __syncthreads() would emit s_waitcnt vmcnt(0), killing the
// cross-iteration global prefetch (measured: round-4 regression 129->140us).
// The "memory" clobber pins memory ops on their side of the barrier.
__device__ __forceinline__ void barrier_lgkm() {
    asm volatile("s_waitcnt lgkmcnt(0)\n\ts_barrier" ::: "memory");
}

// One block per (b,c), looping t=0..15.
//  - temporal history (t-1, t-2) in registers -> temporal taps are free
//  - plane t+1 prefetched into registers; lgkm-only barriers keep those
//    loads in flight across the barrier, so the HBM read stream overlaps
//    compute(t); the vmcnt wait lands at the cur<-nxt rotation after compute
//  - spatial taps via full-plane LDS buffer with 16-col replicate halo
__global__ __launch_bounds__(1024, 4) void lap_st_kernel(
    const float* __restrict__ u,
    const float* __restrict__ Ds,   // (3, 64)
    const float* __restrict__ Dt,   // (2, 64)
    float* __restrict__ out)
{
    __shared__ __align__(16) float sm[HH * PW];

    const int bc = blockIdx.x;             // b*C + c, 0..255
    const int c  = bc & (CC - 1);
    const int tid = threadIdx.x;

    const float cs0 = softplus_f(Ds[0 * CC + c]);
    const float cs1 = softplus_f(Ds[1 * CC + c]);
    const float cs2 = softplus_f(Ds[2 * CC + c]);
    const float ct0 = softplus_f(Dt[0 * CC + c]);
    const float ct1 = softplus_f(Dt[1 * CC + c]);
    const float cu = -4.0f * (cs0 + cs1 + cs2) - (ct0 + ct1);

    const size_t bc_off = (size_t)bc * TT * (HH * WW);

    float4 nxt[4], cur[4], pm1[4], pm2[4];

    // prologue: load plane 0 into cur; causal clamp u[-1]=u[-2]=u[0]
    {
        const float4* up4 = (const float4*)(u + bc_off);
        #pragma unroll
        for (int i = 0; i < 4; ++i) cur[i] = up4[tid + (i << 10)];
        #pragma unroll
        for (int i = 0; i < 4; ++i) { pm1[i] = cur[i]; pm2[i] = cur[i]; }
    }

    for (int t = 0; t < TT; ++t) {
        f32x4* out4 = (f32x4*)(out + bc_off + (size_t)t * (HH * WW));

        barrier_lgkm();   // prev iteration's LDS reads done -> safe to overwrite sm

        // ---- prefetch plane t+1 (issue only; completes during compute) ----
        if (t < TT - 1) {
            const float4* up4 = (const float4*)(u + bc_off + (size_t)(t + 1) * (HH * WW));
            #pragma unroll
            for (int i = 0; i < 4; ++i) nxt[i] = up4[tid + (i << 10)];
        }

        // ---- stage plane t into LDS from registers; halos splatted inline ----
        #pragma unroll
        for (int i = 0; i < 4; ++i) {
            const int k = tid + (i << 10);       // chunk index 0..4095
            const float4 v = cur[i];
            const int row  = k >> 5;             // 32 float4-chunks per row
            const int colc = k & 31;
            *(float4*)&sm[row * PW + HALO + (colc << 2)] = v;
            if (colc == 0) {                      // left replicate halo
                float4 s = make_float4(v.x, v.x, v.x, v.x);
                float* hp = &sm[row * PW];
                *(float4*)&hp[0] = s; *(float4*)&hp[4] = s;
                *(float4*)&hp[8] = s; *(float4*)&hp[12] = s;
            } else if (colc == 31) {              // right replicate halo
                float4 s = make_float4(v.w, v.w, v.w, v.w);
                float* hp = &sm[row * PW + HALO + WW];
                *(float4*)&hp[0] = s; *(float4*)&hp[4] = s;
                *(float4*)&hp[8] = s; *(float4*)&hp[12] = s;
            }
        }

        barrier_lgkm();   // LDS writes visible; prefetch loads still in flight

        // ---- compute ----
        #pragma unroll
        for (int i = 0; i < 4; ++i) {
            const int k   = tid + (i << 10);
            const int row = k >> 5;
            const int col = (k & 31) << 2;
            const float* rp = &sm[row * PW + HALO];

            const int rU1  = (row >= 1)       ? row - 1  : 0;
            const int rD1  = (row <= HH - 2)  ? row + 1  : HH - 1;
            const int rU4  = (row >= 4)       ? row - 4  : 0;
            const int rD4  = (row <= HH - 5)  ? row + 4  : HH - 1;
            const int rU16 = (row >= 16)      ? row - 16 : 0;
            const int rD16 = (row <= HH - 17) ? row + 16 : HH - 1;

            const float4 c0   = cur[i];   // center from registers
            const float4 vu1  = *(const float4*)&sm[rU1  * PW + HALO + col];
            const float4 vd1  = *(const float4*)&sm[rD1  * PW + HALO + col];
            const float4 vu4  = *(const float4*)&sm[rU4  * PW + HALO + col];
            const float4 vd4  = *(const float4*)&sm[rD4  * PW + HALO + col];
            const float4 vu16 = *(const float4*)&sm[rU16 * PW + HALO + col];
            const float4 vd16 = *(const float4*)&sm[rD16 * PW + HALO + col];
            const float4 l4   = *(const float4*)&rp[col - 4];
            const float4 r4   = *(const float4*)&rp[col + 4];
            const float4 l16  = *(const float4*)&rp[col - 16];
            const float4 r16  = *(const float4*)&rp[col + 16];

            const float4 p1 = pm1[i];
            const float4 p2 = pm2[i];

            f32x4 o;
            o.x = cs0 * (vu1.x + vd1.x + l4.w + c0.y)
                + cs1 * (vu4.x + vd4.x + l4.x + r4.x)
                + cs2 * (vu16.x + vd16.x + l16.x + r16.x)
                + cu * c0.x + ct0 * p1.x + ct1 * p2.x;
            o.y = cs0 * (vu1.y + vd1.y + c0.x + c0.z)
                + cs1 * (vu4.y + vd4.y + l4.y + r4.y)
                + cs2 * (vu16.y + vd16.y + l16.y + r16.y)
                + cu * c0.y + ct0 * p1.y + ct1 * p2.y;
            o.z = cs0 * (vu1.z + vd1.z + c0.y + c0.w)
                + cs1 * (vu4.z + vd4.z + l4.z + r4.z)
                + cs2 * (vu16.z + vd16.z + l16.z + r16.z)
                + cu * c0.z + ct0 * p1.z + ct1 * p2.z;
            o.w = cs0 * (vu1.w + vd1.w + c0.z + r4.x)
                + cs1 * (vu4.w + vd4.w + l4.w + r4.w)
                + cs2 * (vu16.w + vd16.w + l16.w + r16.w)
                + cu * c0.w + ct0 * p1.w + ct1 * p2.w;

            __builtin_nontemporal_store(o, &out4[k]);   // streaming output, never re-read
        }

        // rotate temporal history; cur <- nxt is where the vmcnt wait lands
        if (t < TT - 1) {
            #pragma unroll
            for (int i = 0; i < 4; ++i) { pm2[i] = pm1[i]; pm1[i] = cur[i]; cur[i] = nxt[i]; }
        }
    }
}

extern "C" void kernel_launch(void* const* d_in, const int* in_sizes, int n_in,
                              void* d_out, int out_size, void* d_ws, size_t ws_size,
                              hipStream_t stream) {
    const float* u  = (const float*)d_in[0];
    const float* Ds = (const float*)d_in[1];
    const float* Dt = (const float*)d_in[2];
    float* out = (float*)d_out;

    const int nblocks = BB * CC;   // 256 -> one block per CU
    lap_st_kernel<<<dim3(nblocks), dim3(1024), 0, stream>>>(u, Ds, Dt, out);
}